// Round 3
// baseline (150.772 us; speedup 1.0000x reference)
//
#include <hip/hip_runtime.h>

// LocallyConnected1d via bf16 MFMA: out[b,o,l] = sum_{i,k} x[b,i,l+k-4]*w[i,o,k,l] + bias[o,l]
// 512 per-l GEMMs (M=b=64, N=o (8 real, 8 zero-padded), K=576 k-major).
//
// R11: two independent blocks per CU (R10 post-mortem: steps are ~2.6us vs
// ~1us of accounted pipe work; 1 block/CU = single barrier domain, so every
// stall -- x-stage episodes, barrier convergence, dispatch imbalance at
// grid==CU-count -- is unhidden. Occupancy 34% < 50% confirms).
//  * b-split: each block handles 32 of 64 b (outputs disjoint, no atomics).
//    Xs: [24 lw][32 b][XBS] = 60 KB; Bs: BLS 328->320 (o rows exactly fill);
//    zero chunk moved into Xs pad cols 32..39 (never written by stagers).
//    LDS = exactly 81920 B -> 2 blocks/CU.
//  * grid 512: blockIdx = lt*16 + bh*8 + os. bh-pairs (+-8) and lt line-mates
//    (+-16) keep blockIdx mod 8, i.e. same XCD: doubled weight demand merges
//    in L2, HBM FETCH stays ~70 MB.
//  * 8 waves/block (512 thr): all threads stage weights; bt = wvid&1 (2
//    b-tiles), lg = wvid>>1 (4 l-groups). Ring/step schedule unchanged.
//  * BAR() kept (lgkm-only barrier, R10-verified neutral-or-better).

#define CIN   64
#define COUT  64
#define SEQ   512
#define KS    9
#define LT    16
#define OT    8
#define LWIN  24
#define BB    32                       // b per block
#define WSTR  (COUT*KS*SEQ)            // weight i-stride (floats)
#define XBS   40                       // Xs b-stride (ush): 32 i + 8 pad (bank stride 20: conflict-free quarter-wave b128)
#define XLW   (BB*XBS)                 // Xs lw-stride = 1280 ush
#define XS_ELEMS (LWIN*XLW)            // 30720 ush = 60 KB
#define BOS   40                       // Bs o-stride (ush)
#define BLS   (OT*BOS)                 // Bs l-stride = 320 ush
#define BSLOT (LT*BLS)                 // 5120 ush per buffer
#define LDS_USH (XS_ELEMS + 2*BSLOT)   // 40960 ush
#define LDS_BYTES (LDS_USH*2)          // 81920 B -> 2 blocks/CU
#define ZCOL  32                       // zero chunk: Xs row 0, b 0, cols 32..39
#define NSTEP 18                       // 2 i-halves x 9 k-taps

typedef __attribute__((ext_vector_type(8))) short bf16x8;
typedef __attribute__((ext_vector_type(4))) float f32x4;

__device__ __forceinline__ uint pack2bf(float a0, float a1) {
    uint u0 = __float_as_uint(a0) + 0x8000u;
    uint u1 = __float_as_uint(a1) + 0x8000u;
    return __builtin_amdgcn_perm(u1, u0, 0x07060302);  // (bf(a1)<<16)|bf(a0)
}

// Relaxed barrier: drain LDS only; global loads stay in flight across it.
#define BAR() do {                                                           \
    asm volatile("s_waitcnt lgkmcnt(0)" ::: "memory");                       \
    __builtin_amdgcn_s_barrier();                                            \
    asm volatile("" ::: "memory");                                           \
} while (0)

__global__ __launch_bounds__(512, 4)
void lc1d_mfma(const float* __restrict__ x, const float* __restrict__ w,
               const float* __restrict__ bias, float* __restrict__ out)
{
    extern __shared__ ushort lds[];
    ushort* Xs = lds;                    // [lw 0..23][b 0..31][ii 0..31 +pad]
    ushort* BsB = lds + XS_ELEMS;        // 2 x [l 0..15][o 0..7][kk 0..31 +pad]

    const int tid  = threadIdx.x;
    const int lane = tid & 63;
    const int wvid = tid >> 6;           // 0..7
    const int bt = wvid & 1;             // wave's b-tile (16 b)
    const int lg = wvid >> 1;            // wave's l-group (4 l)
    const int lt = blockIdx.x >> 4;      // 0..31
    const int bh = (blockIdx.x >> 3) & 1;// b-half
    const int os = blockIdx.x & 7;       // 0..7 == XCD id
    const int l0 = lt * LT;
    const int o0 = os * OT;

    // ---- weight stager mapping (all 512 threads): 64-B-contiguous l spans --
    const int lf  = tid & 3;             // float4 within the 16-l span
    const int oo  = (tid >> 2) & 7;      // o
    const int ipp = (tid >> 5) & 15;     // i-pair within 32-i half

    const float* wbase = w + ((size_t)(2*ipp)*COUT + (o0 + oo))*(KS*SEQ) + l0 + lf*4;

    float4 rA[3], rB[3];                 // 3-slot ring, i-pair per slot

    // step s: ih = s/9 (i-half), k = s%9 (tap)
    #define LOAD_RING(sl, s) if ((s) < NSTEP) {                                  \
        const int ih_ = (s) / 9, k_ = (s) - 9*ih_;                               \
        const float* p_ = wbase + (size_t)ih_*32*WSTR + k_*SEQ;                  \
        rA[sl] = *(const float4*)p_;                                             \
        rB[sl] = *(const float4*)(p_ + WSTR);                                    \
    }

    // transpose+cvt ring slot -> Bs parity (s&1): b32 of i-pair at [l][o][kk]
    #define WRITE_BS(sl, s) {                                                    \
        ushort* dst_ = BsB + ((s)&1)*BSLOT + oo*BOS + 2*ipp;                     \
        _Pragma("unroll")                                                        \
        for (int dl = 0; dl < 4; ++dl) {                                         \
            uint pk_ = pack2bf((&rA[sl].x)[dl], (&rB[sl].x)[dl]);                \
            *(uint*)(dst_ + (lf*4+dl)*BLS) = pk_;                                \
        }                                                                        \
    }

    // stage Xs for i-half ih: Xs[lw][b][ii] = bf16(x[bh*32+b, ih*32+ii, l0-4+lw])
    // thread = (qq = l-quad 0..5 of 8, rp = (b, ii-pair)); pack ii-pairs -> b32.
    #define STAGE_XS(ih) {                                                       \
        const int qq  = tid & 7;                                                 \
        const int rp0 = tid >> 3;                                                \
        if (qq < 6) {                                                            \
            _Pragma("unroll")                                                    \
            for (int it = 0; it < 8; ++it) {                                     \
                const int rp = rp0 + it*64;                                      \
                const int b_ = rp >> 4, ip_ = rp & 15;                           \
                const float* s0 = x + ((size_t)((bh*BB + b_)*CIN) + (ih)*32      \
                                       + 2*ip_)*SEQ + (l0 - 4) + qq*4;           \
                float4 v0 = make_float4(0.f,0.f,0.f,0.f), v1 = v0;               \
                if (!((lt == 0 && qq == 0) || (lt == 31 && qq == 5))) {          \
                    v0 = *(const float4*)s0;                                     \
                    v1 = *(const float4*)(s0 + SEQ);                             \
                }                                                                \
                ushort* d_ = Xs + b_*XBS + 2*ip_;                                \
                _Pragma("unroll")                                                \
                for (int dl = 0; dl < 4; ++dl)                                   \
                    *(uint*)(d_ + (qq*4+dl)*XLW) = pack2bf((&v0.x)[dl],          \
                                                           (&v1.x)[dl]);         \
            }                                                                    \
        }                                                                        \
    }

    // MFMA lane constants
    const int aoff = (bt*16 + (lane & 15))*XBS + (lane >> 4)*8;
    const int boff = (lane & 15)*BOS + (lane >> 4)*8;
    const bool nhi = (lane & 15) >= 8;                 // dead o lanes -> zeros
    const ushort* zptr = lds + ZCOL;                   // broadcast 16-B zeros

    f32x4 acc[4];
    #pragma unroll
    for (int j = 0; j < 4; ++j) acc[j] = (f32x4)0.0f;

    #define DO_MFMA(s) {                                                         \
        const int k_ = (s) % 9;                                                  \
        const ushort* BsS = BsB + ((s)&1)*BSLOT;                                 \
        _Pragma("unroll")                                                        \
        for (int dl = 0; dl < 4; ++dl) {                                         \
            const int ll = lg*4 + dl;                                            \
            bf16x8 Af = *(const bf16x8*)(Xs + (ll + k_)*XLW + aoff);             \
            const ushort* Bp = nhi ? zptr : (BsS + ll*BLS + boff);               \
            bf16x8 Bf = *(const bf16x8*)Bp;                                      \
            acc[dl] = __builtin_amdgcn_mfma_f32_16x16x32_bf16(Af, Bf, acc[dl],   \
                                                              0, 0, 0);          \
        }                                                                        \
    }

    // one barrier per step: during step s, stagers fill Bs parity (s+1)&1.
    #define STEP(s) {                                                            \
        if ((s) < NSTEP-1) WRITE_BS(((s)+1)%3, (s)+1)                            \
        LOAD_RING(((s)+1)%3, (s)+4)                                              \
        DO_MFMA(s)                                                               \
        BAR();                                                                   \
    }

    // ---- prologue ----
    LOAD_RING(0, 0)
    LOAD_RING(1, 1)
    LOAD_RING(2, 2)
    if (tid < 8) lds[ZCOL + tid] = 0;    // Xs pad cols 32..39 of row 0, b 0
    STAGE_XS(0)
    WRITE_BS(0, 0)
    LOAD_RING(0, 3)
    BAR();             // Xs(ih0) + Bs(step0) + zero chunk ready

    STEP(0)  STEP(1)  STEP(2)  STEP(3)  STEP(4)
    STEP(5)  STEP(6)  STEP(7)  STEP(8)

    STAGE_XS(1)        // all step-8 Xs reads completed at STEP(8)'s barrier
    BAR();

    STEP(9)  STEP(10) STEP(11) STEP(12) STEP(13)
    STEP(14) STEP(15) STEP(16) STEP(17)

    // ---- epilogue: C col = o' = lane&15 (store only o'<8), row = b_local ----
    if (!nhi) {
        const int og = o0 + (lane & 15);
        const int rb = (lane >> 4)*4;
        #pragma unroll
        for (int dl = 0; dl < 4; ++dl) {
            const int lgl = l0 + lg*4 + dl;
            const float bv = bias[og*SEQ + lgl];
            #pragma unroll
            for (int r = 0; r < 4; ++r) {
                const int bg = bh*BB + bt*16 + rb + r;
                out[((size_t)(bg*COUT + og))*SEQ + lgl] = acc[dl][r] + bv;
            }
        }
    }
}

extern "C" void kernel_launch(void* const* d_in, const int* in_sizes, int n_in,
                              void* d_out, int out_size, void* d_ws, size_t ws_size,
                              hipStream_t stream) {
    const float* x    = (const float*)d_in[0];
    const float* wgt  = (const float*)d_in[1];
    const float* bias = (const float*)d_in[2];
    float* out        = (float*)d_out;

    hipFuncSetAttribute((const void*)lc1d_mfma,
                        hipFuncAttributeMaxDynamicSharedMemorySize, LDS_BYTES);
    dim3 grid(512);   // blockIdx = lt*16 + bh*8 + os: mod-8 = XCD preserved
    lc1d_mfma<<<grid, 512, LDS_BYTES, stream>>>(x, wgt, bias, out);
}

// Round 4
// 135.792 us; speedup vs baseline: 1.1103x; 1.1103x over previous
//
#include <hip/hip_runtime.h>

// LocallyConnected1d via bf16 MFMA: out[b,o,l] = sum_{i,k} x[b,i,l+k-4]*w[i,o,k,l] + bias[o,l]
// 512 per-l GEMMs (M=b=64, N=o (8 real, 8 zero-padded), K=576 k-major).
//
// R12 = R10 base (1024 thr, 64 b, 1 block/CU) + two changes:
//  1. 2 k-taps per step: 18 -> 10 MFMA steps, 20 -> 12 barriers. Same LDS/MFMA
//     totals, half the per-step fixed overhead (barrier convergence, lgkm
//     drain, WRITE_BS wait episodes). Bs becomes 4 single-tap buffers
//     (parity*2 + tap), ring is 2 slots x 2 taps (32 VGPR).
//  2. STAGE_XS 6-way bank conflict fix (audit: (qq*4+dl)*XLW stride has
//     XLW*2 = 0 mod 32 banks -> 6 qq-lanes per bank). Rotate each Xs row's
//     four 8-ush ks-groups by (row>>2)&3. Read side free: A-read row ll+k is
//     wave-uniform, so the rotation is just ks' = (ks + (row>>2)) & 3.
//     SQ_LDS_BANK_CONFLICT 6.0M (= ~10us/CU, 21% of dur) -> pred ~2.5M.
//  BLS 328 -> 312 so 4 buffers fit: LDS = 162944 B (< 163840, 1 block/CU --
//  R11 lesson: exact-capacity packing fails, don't bet on 2 blocks).

#define CIN   64
#define COUT  64
#define SEQ   512
#define KS    9
#define LT    16
#define OT    8
#define LWIN  24
#define WSTR  (COUT*KS*SEQ)            // weight i-stride (floats)
#define XBS   40                       // Xs b-stride (ush): 32 i + 8 pad
#define XLW   (64*XBS)                 // Xs lw-stride = 2560 ush
#define XS_ELEMS (LWIN*XLW)            // 61440 ush = 120 KB
#define BOS   40                       // Bs o-stride (ush)
#define BLS   312                      // Bs l-stride (ush), 16-B aligned
#define BSLOT (LT*BLS)                 // 4992 ush per tap-buffer
#define NBUF  4                        // (step parity)*2 + tap
#define ZOFF  (XS_ELEMS + NBUF*BSLOT)  // 81408: zero region for n>=8 B reads
#define LDS_USH (ZOFF + 64)            // 81472 ush
#define LDS_BYTES (LDS_USH*2)          // 162944 B -> 1 block/CU
#define NSTEP2 10                      // 2 i-halves x 5 merged steps

// step s: ih = s<5?0:1, k0 = 2*(s%5), ntap = (s%5==4)?1:2
#define S_IH(s) ((s) < 5 ? 0 : 1)
#define S_K0(s) ((((s) < 5) ? (s) : (s)-5) * 2)
#define S_NT(s) (((((s) < 5) ? (s) : (s)-5) == 4) ? 1 : 2)

typedef __attribute__((ext_vector_type(8))) short bf16x8;
typedef __attribute__((ext_vector_type(4))) float f32x4;

__device__ __forceinline__ uint pack2bf(float a0, float a1) {
    uint u0 = __float_as_uint(a0) + 0x8000u;
    uint u1 = __float_as_uint(a1) + 0x8000u;
    return __builtin_amdgcn_perm(u1, u0, 0x07060302);  // (bf(a1)<<16)|bf(a0)
}

// Relaxed barrier: drain LDS only; global loads stay in flight across it.
#define BAR() do {                                                           \
    asm volatile("s_waitcnt lgkmcnt(0)" ::: "memory");                       \
    __builtin_amdgcn_s_barrier();                                            \
    asm volatile("" ::: "memory");                                           \
} while (0)

__global__ __launch_bounds__(1024, 4)
void lc1d_mfma(const float* __restrict__ x, const float* __restrict__ w,
               const float* __restrict__ bias, float* __restrict__ out)
{
    extern __shared__ ushort lds[];
    ushort* Xs = lds;                    // [lw 0..23][b 0..63][ks-rotated 32 + pad]
    ushort* BsB = lds + XS_ELEMS;        // 4 x [l 0..15][o 0..7][kk 0..31]

    const int tid  = threadIdx.x;
    const int lane = tid & 63;
    const int wvid = tid >> 6;           // 0..15
    const int bt = wvid & 3;             // wave's b-tile (16 b)
    const int lg = wvid >> 2;            // wave's l-group (4 l)
    const int lt = blockIdx.x >> 3;      // 0..31
    const int os = blockIdx.x & 7;       // 0..7 == XCD id
    const int l0 = lt * LT;
    const int o0 = os * OT;

    // ---- weight stager mapping (tid < 512): 64-B-contiguous l spans ----
    const bool stager = (tid < 512);
    const int lf  = tid & 3;             // float4 within the 16-l span
    const int oo  = (tid >> 2) & 7;      // o
    const int ipp = (tid >> 5) & 15;     // i-pair within 32-i half

    const float* wbase = w + ((size_t)(2*ipp)*COUT + (o0 + oo))*(KS*SEQ) + l0 + lf*4;

    float4 rA[2][2], rB[2][2];           // 2-slot ring x 2 taps

    #define LOAD_TAP(sl, t, ih, k) {                                             \
        const float* p_ = wbase + (size_t)(ih)*32*WSTR + (k)*SEQ;                \
        rA[sl][t] = *(const float4*)p_;                                          \
        rB[sl][t] = *(const float4*)(p_ + WSTR);                                 \
    }
    #define LOAD_RING2(sl, s) if (stager && (s) < NSTEP2) {                      \
        LOAD_TAP(sl, 0, S_IH(s), S_K0(s))                                        \
        if (S_NT(s) == 2) LOAD_TAP(sl, 1, S_IH(s), S_K0(s)+1)                    \
    }

    // transpose+cvt ring tap -> Bs buffer bi: b32 of i-pair at [l][o][kk]
    #define WRITE_TAP(sl, t, bi) {                                               \
        ushort* dst_ = BsB + (bi)*BSLOT + oo*BOS + 2*ipp;                        \
        _Pragma("unroll")                                                        \
        for (int dl = 0; dl < 4; ++dl) {                                         \
            uint pk_ = pack2bf((&rA[sl][t].x)[dl], (&rB[sl][t].x)[dl]);          \
            *(uint*)(dst_ + (lf*4+dl)*BLS) = pk_;                                \
        }                                                                        \
    }
    #define WRITE_BS2(sl, s) if (stager) {                                       \
        WRITE_TAP(sl, 0, ((s)&1)*2)                                              \
        if (S_NT(s) == 2) WRITE_TAP(sl, 1, ((s)&1)*2 + 1)                        \
    }

    // stage Xs for i-half ih: Xs[lw][b][rot(ii)] = bf16(x[b, ih*32+ii, l0-4+lw])
    // rot: row lw keeps its four 8-ush ks-groups rotated by (lw>>2)&3 == qq&3,
    // so the 6 qq-lanes of a (b,ip) group hit different banks (was 6-way).
    #define STAGE_XS(ih) {                                                       \
        const int qq  = tid & 7;                                                 \
        const int rp0 = tid >> 3;                                                \
        const int cr_ = (qq & 3) << 3;                                           \
        if (qq < 6) {                                                            \
            _Pragma("unroll")                                                    \
            for (int it = 0; it < 8; ++it) {                                     \
                const int rp = rp0 + it*128;                                     \
                const int b_ = rp >> 4, ip_ = rp & 15;                           \
                const float* s0 = x + ((size_t)(b_*CIN) + (ih)*32 + 2*ip_)*SEQ   \
                                    + (l0 - 4) + qq*4;                           \
                float4 v0 = make_float4(0.f,0.f,0.f,0.f), v1 = v0;               \
                if (!((lt == 0 && qq == 0) || (lt == 31 && qq == 5))) {          \
                    v0 = *(const float4*)s0;                                     \
                    v1 = *(const float4*)(s0 + SEQ);                             \
                }                                                                \
                ushort* d_ = Xs + b_*XBS + ((2*ip_ + cr_) & 31);                 \
                _Pragma("unroll")                                                \
                for (int dl = 0; dl < 4; ++dl)                                   \
                    *(uint*)(d_ + (qq*4+dl)*XLW) = pack2bf((&v0.x)[dl],          \
                                                           (&v1.x)[dl]);         \
            }                                                                    \
        }                                                                        \
    }

    // MFMA lane constants
    const int abase = (bt*16 + (lane & 15))*XBS;
    const int ks_   = lane >> 4;
    const int boff  = (lane & 15)*BOS + ks_*8;
    const bool nhi  = (lane & 15) >= 8;                // dead o lanes -> zeros
    const ushort* zptr = lds + ZOFF + ks_*8;           // broadcast zeros

    f32x4 acc[4];
    #pragma unroll
    for (int j = 0; j < 4; ++j) acc[j] = (f32x4)0.0f;

    #define DO_TAP(bi, k) {                                                      \
        _Pragma("unroll")                                                        \
        for (int dl = 0; dl < 4; ++dl) {                                         \
            const int ll  = lg*4 + dl;                                           \
            const int row = ll + (k);                                            \
            const int col = ((ks_ + (row >> 2)) & 3) << 3;                       \
            bf16x8 Af = *(const bf16x8*)(Xs + row*XLW + abase + col);            \
            const ushort* Bp = nhi ? zptr : (BsB + (bi)*BSLOT + ll*BLS + boff);  \
            bf16x8 Bf = *(const bf16x8*)Bp;                                      \
            acc[dl] = __builtin_amdgcn_mfma_f32_16x16x32_bf16(Af, Bf, acc[dl],   \
                                                              0, 0, 0);          \
        }                                                                        \
    }
    #define DO_MFMA2(s) {                                                        \
        DO_TAP(((s)&1)*2, S_K0(s))                                               \
        if (S_NT(s) == 2) DO_TAP(((s)&1)*2 + 1, S_K0(s)+1)                       \
    }

    // one barrier per merged step; during step s, stagers fill step s+1's
    // buffers (parity (s+1)&1) from ring slot (s+1)&1, loaded at step s-1.
    #define STEP2(s) {                                                           \
        if ((s)+1 < NSTEP2) WRITE_BS2(((s)+1)&1, (s)+1)                          \
        if ((s)+2 < NSTEP2) LOAD_RING2((s)&1, (s)+2)                             \
        DO_MFMA2(s)                                                              \
        BAR();                                                                   \
    }

    // ---- prologue ----
    LOAD_RING2(0, 0)
    LOAD_RING2(1, 1)
    if (tid < 64) lds[ZOFF + tid] = 0;
    STAGE_XS(0)
    WRITE_BS2(0, 0)
    BAR();             // Xs(ih0) + Bs(step0) + zero region ready

    STEP2(0)  STEP2(1)  STEP2(2)  STEP2(3)  STEP2(4)

    STAGE_XS(1)        // all half-0 Xs reads completed at STEP2(4)'s barrier
    BAR();             // (step-5 Bs already written at step 4)

    STEP2(5)  STEP2(6)  STEP2(7)  STEP2(8)  STEP2(9)

    // ---- epilogue: C col = o' = lane&15 (store only o'<8), row = b_local ----
    if (!nhi) {
        const int og = o0 + (lane & 15);
        const int rb = ks_*4;
        #pragma unroll
        for (int dl = 0; dl < 4; ++dl) {
            const int lgl = l0 + lg*4 + dl;
            const float bv = bias[og*SEQ + lgl];
            #pragma unroll
            for (int r = 0; r < 4; ++r) {
                const int bg = bt*16 + rb + r;
                out[((size_t)(bg*COUT + og))*SEQ + lgl] = acc[dl][r] + bv;
            }
        }
    }
}

extern "C" void kernel_launch(void* const* d_in, const int* in_sizes, int n_in,
                              void* d_out, int out_size, void* d_ws, size_t ws_size,
                              hipStream_t stream) {
    const float* x    = (const float*)d_in[0];
    const float* wgt  = (const float*)d_in[1];
    const float* bias = (const float*)d_in[2];
    float* out        = (float*)d_out;

    hipFuncSetAttribute((const void*)lc1d_mfma,
                        hipFuncAttributeMaxDynamicSharedMemorySize, LDS_BYTES);
    dim3 grid(256);   // blockIdx = lt*8 + os: os == XCD id; lt line-mates co-XCD
    lc1d_mfma<<<grid, 1024, LDS_BYTES, stream>>>(x, wgt, bias, out);
}